// Round 3
// baseline (353.299 us; speedup 1.0000x reference)
//
#include <hip/hip_runtime.h>
#include <hip/hip_bf16.h>
#include <type_traits>

#define NN 100000
#define NE 800000
#define HD 128
#define BN_EPS 1e-5f
#define NB_E_C 3125   // (NE+255)/256
#define NB_N_C 391    // (NN+255)/256
#define NKB 16        // src buckets for in-node edge sort
#define KBW 6250      // nodes per src bucket (NN/NKB)

typedef __bf16 bf16x8 __attribute__((ext_vector_type(8)));
typedef float  f32x4  __attribute__((ext_vector_type(4)));
typedef float  f32x2  __attribute__((ext_vector_type(2)));

// ---------------- CSR build ----------------

// fused: per-(dst,srcbucket) histogram+rank (blocks 0..NB_E_C-1),
// weight transpose (3 blocks), BN affine precompute (1 block)
__global__ __launch_bounds__(256) void count_prep_k(const int* __restrict__ ei, int* __restrict__ count2,
                                                    int* __restrict__ rank2,
                                                    const float* __restrict__ W0, const float* __restrict__ W1,
                                                    const float* __restrict__ W2, __bf16* __restrict__ WT,
                                                    const float* __restrict__ g0, const float* __restrict__ b0,
                                                    const float* __restrict__ m0, const float* __restrict__ v0,
                                                    const float* __restrict__ g1, const float* __restrict__ b1,
                                                    const float* __restrict__ m1, const float* __restrict__ v1,
                                                    float* __restrict__ A0, float* __restrict__ B0,
                                                    float* __restrict__ A1, float* __restrict__ B1) {
    int bid = blockIdx.x;
    int tid = threadIdx.x;
    if (bid < NB_E_C) {
        int e = bid * 256 + tid;
        if (e < NE) {
            int s = ei[e], d = ei[NE + e];
            int kb = s / KBW;
            rank2[e] = atomicAdd(&count2[d * NKB + kb], 1);
        }
    } else if (bid < NB_E_C + 3) {
        int w = bid - NB_E_C;
        const float* Ws[3] = {W0, W1, W2};
        const float* W = Ws[w];
        __bf16* T = WT + w * (HD * HD);
        #pragma unroll 4
        for (int it = 0; it < 64; ++it) {
            int idx = it * 256 + tid;          // idx = n*128 + k (writes coalesced)
            int n = idx >> 7, k = idx & 127;
            T[idx] = (__bf16)W[k * HD + n];
        }
    } else {
        if (tid < 128) {
            float a = g0[tid] * rsqrtf(v0[tid] + BN_EPS);
            A0[tid] = a; B0[tid] = b0[tid] - m0[tid] * a;
        } else {
            int u = tid - 128;
            float a = g1[u] * rsqrtf(v1[u] + BN_EPS);
            A1[u] = a; B1[u] = b1[u] - m1[u] * a;
        }
    }
}

// per node: in-node exclusive prefix over 16 bucket counters (in place),
// degree -> dis/selfn, degree histogram (LDS pre-agg), block scan of degree
__global__ __launch_bounds__(256) void scan1_k(int* __restrict__ count2,
                                               int* __restrict__ rp, int* __restrict__ bsums,
                                               float* __restrict__ dis, float* __restrict__ selfn,
                                               int* __restrict__ hist) {
    __shared__ int sm[256];
    __shared__ int lhist[64];
    int tid = threadIdx.x;
    if (tid < 64) lhist[tid] = 0;
    int i = blockIdx.x * 256 + tid;
    int v = 0;
    if (i < NN) {
        int base = i * NKB;
        int4* c4 = (int4*)&count2[base];
        int4 a = c4[0], b = c4[1], c = c4[2], d = c4[3];
        int run = 0;
        int t;
        t = a.x; a.x = run; run += t;  t = a.y; a.y = run; run += t;
        t = a.z; a.z = run; run += t;  t = a.w; a.w = run; run += t;
        t = b.x; b.x = run; run += t;  t = b.y; b.y = run; run += t;
        t = b.z; b.z = run; run += t;  t = b.w; b.w = run; run += t;
        t = c.x; c.x = run; run += t;  t = c.y; c.y = run; run += t;
        t = c.z; c.z = run; run += t;  t = c.w; c.w = run; run += t;
        t = d.x; d.x = run; run += t;  t = d.y; d.y = run; run += t;
        t = d.z; d.z = run; run += t;  t = d.w; d.w = run; run += t;
        c4[0] = a; c4[1] = b; c4[2] = c; c4[3] = d;
        v = run;                        // degree
        float deg = (float)v + 1.0f;
        float di = rsqrtf(deg);
        dis[i] = di;
        selfn[i] = di * di;
    }
    __syncthreads();
    if (i < NN) atomicAdd(&lhist[min(v, 63)], 1);
    sm[tid] = v; __syncthreads();
    for (int off = 1; off < 256; off <<= 1) {
        int t = (tid >= off) ? sm[tid - off] : 0;
        __syncthreads();
        sm[tid] += t;
        __syncthreads();
    }
    if (i < NN) rp[i] = sm[tid] - v;           // exclusive within block
    if (tid == 255) bsums[blockIdx.x] = sm[tid];
    if (tid < 64 && lhist[tid]) atomicAdd(&hist[tid], lhist[tid]);
}

// fused scan2+scan3: every block redundantly reduces bsums[0..blockIdx)
__global__ __launch_bounds__(256) void scan23_k(int* __restrict__ rp, const int* __restrict__ bsums, int nb) {
    __shared__ int sm[256];
    int tid = threadIdx.x;
    int b = blockIdx.x;
    int partial = 0;
    for (int i = tid; i < b; i += 256) partial += bsums[i];
    sm[tid] = partial; __syncthreads();
    #pragma unroll
    for (int off = 128; off > 0; off >>= 1) {
        if (tid < off) sm[tid] += sm[tid + off];
        __syncthreads();
    }
    int prefix = sm[0];
    int i = b * 256 + tid;
    if (i < NN) rp[i] += prefix;
    if (i == 0) rp[NN] = NE;
}

// scatter edges into CSR, src-bucket-sorted within each dst (no atomics on
// position: pos = rp[d] + in-node bucket offset + rank within bucket).
// Extra blocks: degree-sorted node permutation (counting sort, LDS pre-agg).
__global__ __launch_bounds__(256) void scatter_k(const int* __restrict__ ei, const int* __restrict__ rp,
                                                 const int* __restrict__ count2, const int* __restrict__ rank2,
                                                 const float* __restrict__ dis,
                                                 uint2* __restrict__ edges,
                                                 const int* __restrict__ hist, int* __restrict__ histcnt,
                                                 int* __restrict__ perm) {
    int bid = blockIdx.x;
    int tid = threadIdx.x;
    if (bid < NB_E_C) {
        int e = bid * 256 + tid;
        if (e >= NE) return;
        int s = ei[e], d = ei[NE + e];
        int kb = s / KBW;
        int pos = rp[d] + count2[d * NKB + kb] + rank2[e];
        edges[pos] = make_uint2((unsigned)s, __float_as_uint(dis[s] * dis[d]));
    } else {
        __shared__ int lh[64];
        __shared__ int gb[64];
        __shared__ int lhist[64];
        if (tid < 64) { lh[tid] = 0; lhist[tid] = hist[tid]; }
        __syncthreads();
        int i = (bid - NB_E_C) * 256 + tid;
        int bin = 0, lrank = 0;
        if (i < NN) {
            int deg = rp[i + 1] - rp[i];
            bin = min(deg, 63);
            lrank = atomicAdd(&lh[bin], 1);
        }
        __syncthreads();
        if (tid < 64 && lh[tid]) gb[tid] = atomicAdd(&histcnt[tid], lh[tid]);
        __syncthreads();
        if (i < NN) {
            int pf = 0;
            for (int j = 0; j < bin; ++j) pf += lhist[j];   // global bin prefix
            perm[pf + gb[bin] + lrank] = i;
        }
    }
}

// ---------------- GEMM: [N,128] (fp32 or bf16) @ WT[n][k] bf16 -> bf16 ----------------
// One 64-row chunk per block. Column-permuted B mapping: MFMA tile ct, col m
// is fed channel n = m*8+ct, so each thread's 8 accumulator values per output
// row are channels m*8..m*8+7 -> one bf16x8 (16B/lane) coalesced store.

template <typename T>
__global__ __launch_bounds__(256, 5) void gemm128_k(const T* __restrict__ A, const __bf16* __restrict__ WTg,
                                                    __bf16* __restrict__ HW) {
    __shared__ __bf16 WL[128 * 128];   // 32 KiB -> 5 blocks/CU
    const int tid = threadIdx.x;
    const int wid  = __builtin_amdgcn_readfirstlane(tid >> 6);
    const int lane = tid & 63;
    const int m = lane & 15, quad = lane >> 4;
    const int row_base = blockIdx.x * 64 + wid * 16;

    // prefetch this lane's 4 A-fragments (k = ks*32 + quad*8) before the barrier
    int r = row_base + m;
    if (r >= NN) r = NN - 1;
    bf16x8 afr[4];
    if constexpr (std::is_same<T, float>::value) {
        const float4* ap = (const float4*)(A + (size_t)r * HD);
        #pragma unroll
        for (int ks = 0; ks < 4; ++ks) {
            float4 x0 = ap[ks * 8 + quad * 2], x1 = ap[ks * 8 + quad * 2 + 1];
            bf16x8 a;
            a[0] = (__bf16)x0.x; a[1] = (__bf16)x0.y; a[2] = (__bf16)x0.z; a[3] = (__bf16)x0.w;
            a[4] = (__bf16)x1.x; a[5] = (__bf16)x1.y; a[6] = (__bf16)x1.z; a[7] = (__bf16)x1.w;
            afr[ks] = a;
        }
    } else {
        const bf16x8* ap = (const bf16x8*)(A + (size_t)r * HD);
        #pragma unroll
        for (int ks = 0; ks < 4; ++ks) afr[ks] = ap[ks * 4 + quad];
    }

    // stage WT -> LDS with chunk-XOR swizzle: chunk c of row n lands at c^((n>>3)&7)
    #pragma unroll
    for (int it = 0; it < 8; ++it) {
        int id = it * 256 + tid;          // chunk id
        int n = id >> 4, c = id & 15;     // row, 16B-chunk within row
        int cs = c ^ ((n >> 3) & 7);
        *(uint4*)&WL[n * 128 + cs * 8] = *(const uint4*)(WTg + n * HD + c * 8);
    }
    __syncthreads();

    f32x4 acc[8];
    #pragma unroll
    for (int ct = 0; ct < 8; ++ct) acc[ct] = (f32x4){0.f, 0.f, 0.f, 0.f};

    #pragma unroll
    for (int ks = 0; ks < 4; ++ks) {
        #pragma unroll
        for (int ct = 0; ct < 8; ++ct) {
            int n = m * 8 + ct;                       // channel fed to tile ct, col m
            int cs = (ks * 4 + quad) ^ (m & 7);       // swizzled 16B chunk
            bf16x8 bfr = *(const bf16x8*)&WL[n * 128 + cs * 8];
            acc[ct] = __builtin_amdgcn_mfma_f32_16x16x32_bf16(afr[ks], bfr, acc[ct], 0, 0, 0);
        }
    }

    // coalesced epilogue: one bf16x8 (16B) store per lane per row
    #pragma unroll
    for (int rr = 0; rr < 4; ++rr) {
        int row = row_base + quad * 4 + rr;
        if (row < NN) {
            bf16x8 v;
            #pragma unroll
            for (int ct = 0; ct < 8; ++ct) v[ct] = (__bf16)acc[ct][rr];
            *(bf16x8*)(HW + (size_t)row * HD + m * 8) = v;
        }
    }
}

// ---------------- pull aggregation + epilogue ----------------
// Nodes processed in degree-sorted order (perm): the 4 nodes of a wave have
// equal degree (no exec-mask divergence) and equal-degree cohorts march
// through the src-sorted adjacency in phase (L2-resident src slice).
// MODE 0: hb = relu(z); MODE 1: hb = relu(z*A+B) + hb; MODE 2: MODE-1 then
// in-register W3 projection -> hw3.

__device__ __forceinline__ void acc8p(f32x2* acc, uint4 rv, float wt) {
    f32x2 w2 = {wt, wt};
    f32x2 x0 = {__uint_as_float(rv.x << 16), __uint_as_float(rv.x & 0xffff0000u)};
    f32x2 x1 = {__uint_as_float(rv.y << 16), __uint_as_float(rv.y & 0xffff0000u)};
    f32x2 x2 = {__uint_as_float(rv.z << 16), __uint_as_float(rv.z & 0xffff0000u)};
    f32x2 x3 = {__uint_as_float(rv.w << 16), __uint_as_float(rv.w & 0xffff0000u)};
    acc[0] = __builtin_elementwise_fma(x0, w2, acc[0]);
    acc[1] = __builtin_elementwise_fma(x1, w2, acc[1]);
    acc[2] = __builtin_elementwise_fma(x2, w2, acc[2]);
    acc[3] = __builtin_elementwise_fma(x3, w2, acc[3]);
}

__device__ __forceinline__ void unpack8(uint4 rv, float* f) {
    f[0] = __uint_as_float(rv.x << 16);         f[1] = __uint_as_float(rv.x & 0xffff0000u);
    f[2] = __uint_as_float(rv.y << 16);         f[3] = __uint_as_float(rv.y & 0xffff0000u);
    f[4] = __uint_as_float(rv.z << 16);         f[5] = __uint_as_float(rv.z & 0xffff0000u);
    f[6] = __uint_as_float(rv.w << 16);         f[7] = __uint_as_float(rv.w & 0xffff0000u);
}

template <int MODE>
__global__ __launch_bounds__(256) void agg_k(const __bf16* __restrict__ hw, const int* __restrict__ rp,
                                             const uint2* __restrict__ edges, const int* __restrict__ perm,
                                             const float* __restrict__ selfn, const float* __restrict__ bias,
                                             const float* __restrict__ bnA, const float* __restrict__ bnB,
                                             __bf16* __restrict__ hb, const float* __restrict__ W3,
                                             float2* __restrict__ hw3) {
    const int lane = threadIdx.x & 63;
    const int wid  = threadIdx.x >> 6;
    const int grp  = lane >> 4;     // node within the wave
    const int m    = lane & 15;     // 16B chunk within the row (channels 8m..8m+7)
    const int idx = blockIdx.x * 16 + wid * 4 + grp;   // NN = 6250*16 exactly
    const int n = perm[idx];
    const int c0 = m * 8;
    const int L = NE - 1;

    const int e0 = rp[n], e1 = rp[n + 1];

    // issue long-latency independent loads first: self row, residual row
    const float sn = selfn[n];
    uint4 rv_self = *(const uint4*)(hw + ((size_t)n << 7) + c0);
    __bf16* hbp = hb + ((size_t)n << 7) + c0;
    uint4 rv_prev;
    if (MODE != 0) rv_prev = *(const uint4*)hbp;

    f32x2 acc2[4];
    #pragma unroll
    for (int j = 0; j < 4; ++j) acc2[j] = (f32x2){0.f, 0.f};

    // 4-deep pipelined gather loop
    int e = e0;
    int cnt = e1 - e0;
    uint2 edA = edges[min(e,     L)];
    uint2 edB = edges[min(e + 1, L)];
    uint2 edC = edges[min(e + 2, L)];
    uint2 edD = edges[min(e + 3, L)];
    while (cnt >= 4) {
        uint4 r0 = *(const uint4*)(hw + ((size_t)edA.x << 7) + c0);
        uint4 r1 = *(const uint4*)(hw + ((size_t)edB.x << 7) + c0);
        uint4 r2 = *(const uint4*)(hw + ((size_t)edC.x << 7) + c0);
        uint4 r3 = *(const uint4*)(hw + ((size_t)edD.x << 7) + c0);
        uint2 nA = edges[min(e + 4, L)];
        uint2 nB = edges[min(e + 5, L)];
        uint2 nC = edges[min(e + 6, L)];
        uint2 nD = edges[min(e + 7, L)];
        acc8p(acc2, r0, __uint_as_float(edA.y));
        acc8p(acc2, r1, __uint_as_float(edB.y));
        acc8p(acc2, r2, __uint_as_float(edC.y));
        acc8p(acc2, r3, __uint_as_float(edD.y));
        edA = nA; edB = nB; edC = nC; edD = nD;
        e += 4; cnt -= 4;
    }
    if (cnt >= 2) {
        uint4 r0 = *(const uint4*)(hw + ((size_t)edA.x << 7) + c0);
        uint4 r1 = *(const uint4*)(hw + ((size_t)edB.x << 7) + c0);
        acc8p(acc2, r0, __uint_as_float(edA.y));
        acc8p(acc2, r1, __uint_as_float(edB.y));
        edA = edC;           // for the cnt==3 tail
        cnt -= 2;
    }
    if (cnt == 1) {
        uint4 rv = *(const uint4*)(hw + ((size_t)edA.x << 7) + c0);
        acc8p(acc2, rv, __uint_as_float(edA.y));
    }
    acc8p(acc2, rv_self, sn);   // self-loop

    float acc[8] = {acc2[0][0], acc2[0][1], acc2[1][0], acc2[1][1],
                    acc2[2][0], acc2[2][1], acc2[3][0], acc2[3][1]};

    float4 bs0 = *(const float4*)(bias + c0);
    float4 bs1 = *(const float4*)(bias + c0 + 4);
    float z[8] = {acc[0] + bs0.x, acc[1] + bs0.y, acc[2] + bs0.z, acc[3] + bs0.w,
                  acc[4] + bs1.x, acc[5] + bs1.y, acc[6] + bs1.z, acc[7] + bs1.w};

    if (MODE == 0) {
        bf16x8 v;
        #pragma unroll
        for (int j = 0; j < 8; ++j) v[j] = (__bf16)fmaxf(z[j], 0.f);
        *(bf16x8*)hbp = v;
    } else {
        float4 a0v = *(const float4*)(bnA + c0), a1v = *(const float4*)(bnA + c0 + 4);
        float4 b0v = *(const float4*)(bnB + c0), b1v = *(const float4*)(bnB + c0 + 4);
        float Af[8] = {a0v.x, a0v.y, a0v.z, a0v.w, a1v.x, a1v.y, a1v.z, a1v.w};
        float Bf[8] = {b0v.x, b0v.y, b0v.z, b0v.w, b1v.x, b1v.y, b1v.z, b1v.w};
        float pr[8];
        unpack8(rv_prev, pr);
        float hn[8];
        #pragma unroll
        for (int j = 0; j < 8; ++j)
            hn[j] = fmaxf(fmaf(z[j], Af[j], Bf[j]), 0.f) + pr[j];

        if (MODE == 1) {
            bf16x8 v;
            #pragma unroll
            for (int j = 0; j < 8; ++j) v[j] = (__bf16)hn[j];
            *(bf16x8*)hbp = v;
        } else {
            // fused output projection: hw3[n] = hn . W3  (W3 is [128,2] row-major)
            float4 w0 = *(const float4*)(W3 + c0 * 2);
            float4 w1 = *(const float4*)(W3 + c0 * 2 + 4);
            float4 w2 = *(const float4*)(W3 + c0 * 2 + 8);
            float4 w3v = *(const float4*)(W3 + c0 * 2 + 12);
            float p0 = hn[0] * w0.x + hn[1] * w0.z + hn[2] * w1.x + hn[3] * w1.z
                     + hn[4] * w2.x + hn[5] * w2.z + hn[6] * w3v.x + hn[7] * w3v.z;
            float p1 = hn[0] * w0.y + hn[1] * w0.w + hn[2] * w1.y + hn[3] * w1.w
                     + hn[4] * w2.y + hn[5] * w2.w + hn[6] * w3v.y + hn[7] * w3v.w;
            // reduce within the 16-lane group (xor < 16 stays inside the group)
            #pragma unroll
            for (int o = 1; o < 16; o <<= 1) {
                p0 += __shfl_xor(p0, o);
                p1 += __shfl_xor(p1, o);
            }
            if (m == 0) hw3[n] = make_float2(p0, p1);
        }
    }
}

// ---------------- final: aggregate hw3 + log_softmax ----------------

__global__ __launch_bounds__(256) void final_k(const float2* __restrict__ hw3, const int* __restrict__ rp,
                                               const uint2* __restrict__ edges,
                                               const float* __restrict__ selfn, const float* __restrict__ b3,
                                               float* __restrict__ out) {
    int n = blockIdx.x * 256 + threadIdx.x;
    if (n >= NN) return;
    const int L = NE - 1;
    float a0 = 0.f, a1 = 0.f;
    int e0 = rp[n], e1 = rp[n + 1];
    int cnt = e1 - e0;
    // 2-deep pipelined gather
    uint2 edA = edges[min(e0,     L)];
    uint2 edB = edges[min(e0 + 1, L)];
    int e = e0;
    while (cnt >= 2) {
        float2 v0 = hw3[edA.x];
        float2 v1 = hw3[edB.x];
        float w0 = __uint_as_float(edA.y), w1 = __uint_as_float(edB.y);
        edA = edges[min(e + 2, L)];
        edB = edges[min(e + 3, L)];
        a0 = fmaf(w0, v0.x, a0); a1 = fmaf(w0, v0.y, a1);
        a0 = fmaf(w1, v1.x, a0); a1 = fmaf(w1, v1.y, a1);
        e += 2; cnt -= 2;
    }
    if (cnt == 1) {
        float2 v = hw3[edA.x];
        float w = __uint_as_float(edA.y);
        a0 = fmaf(w, v.x, a0); a1 = fmaf(w, v.y, a1);
    }
    float sn = selfn[n];
    float2 hv = hw3[n];
    float z0 = a0 + sn * hv.x + b3[0];
    float z1 = a1 + sn * hv.y + b3[1];
    float mx = fmaxf(z0, z1);
    float l = mx + logf(expf(z0 - mx) + expf(z1 - mx));
    out[n * 2 + 0] = z0 - l;
    out[n * 2 + 1] = z1 - l;
}

// ---------------- launch ----------------

extern "C" void kernel_launch(void* const* d_in, const int* in_sizes, int n_in,
                              void* d_out, int out_size, void* d_ws, size_t ws_size,
                              hipStream_t stream) {
    (void)in_sizes; (void)n_in; (void)out_size; (void)ws_size;

    const float* x   = (const float*)d_in[0];
    const int*   ei  = (const int*)d_in[1];
    const float* W0  = (const float*)d_in[2];
    const float* b0  = (const float*)d_in[3];
    const float* W1  = (const float*)d_in[4];
    const float* b1  = (const float*)d_in[5];
    const float* W2  = (const float*)d_in[6];
    const float* b2  = (const float*)d_in[7];
    const float* W3  = (const float*)d_in[8];
    const float* b3  = (const float*)d_in[9];
    const float* bn0g = (const float*)d_in[10];
    const float* bn0b = (const float*)d_in[11];
    const float* bn0m = (const float*)d_in[12];
    const float* bn0v = (const float*)d_in[13];
    const float* bn1g = (const float*)d_in[14];
    const float* bn1b = (const float*)d_in[15];
    const float* bn1m = (const float*)d_in[16];
    const float* bn1v = (const float*)d_in[17];
    float* out = (float*)d_out;

    char* p = (char*)d_ws;
    auto alloc = [&](size_t bytes) -> void* {
        void* r = (void*)p;
        p += (bytes + 255) & ~(size_t)255;
        return r;
    };
    __bf16*  hb    = (__bf16*)alloc((size_t)NN * HD * 2);   // h in bf16
    __bf16*  hw    = (__bf16*)alloc((size_t)NN * HD * 2);
    float2*  hw3   = (float2*)alloc((size_t)NN * 8);
    float*   dis   = (float*)alloc((size_t)NN * 4);
    float*   selfn = (float*)alloc((size_t)NN * 4);
    int*     count2 = (int*)alloc((size_t)NN * NKB * 4 + 512);  // + hist(64) + histcnt(64)
    int*     hist   = count2 + (size_t)NN * NKB;
    int*     histcnt = hist + 64;
    int*     rp    = (int*)alloc((size_t)(NN + 1) * 4);
    uint2*   edges = (uint2*)alloc((size_t)NE * 8);
    int*     rank2 = (int*)alloc((size_t)NE * 4);
    int*     perm  = (int*)alloc((size_t)NN * 4);
    int*     bsums = (int*)alloc((size_t)512 * 4);
    float*   bnA0  = (float*)alloc(128 * 4);
    float*   bnB0  = (float*)alloc(128 * 4);
    float*   bnA1  = (float*)alloc(128 * 4);
    float*   bnB1  = (float*)alloc(128 * 4);
    __bf16*  WT    = (__bf16*)alloc((size_t)3 * HD * HD * 2);  // transposed bf16 weights

    const int NB_N = NB_N_C;             // 391
    const int NB_G = (NN + 63) / 64;     // 1563 (GEMM: 64 rows/block)
    const int NB_A = (NN + 15) / 16;     // 6250 (agg: 16 nodes per block)

    hipMemsetAsync(count2, 0, (size_t)NN * NKB * 4 + 512, stream);

    count_prep_k<<<NB_E_C + 4, 256, 0, stream>>>(ei, count2, rank2,
                                                 W0, W1, W2, WT,
                                                 bn0g, bn0b, bn0m, bn0v, bn1g, bn1b, bn1m, bn1v,
                                                 bnA0, bnB0, bnA1, bnB1);
    scan1_k<<<NB_N, 256, 0, stream>>>(count2, rp, bsums, dis, selfn, hist);
    scan23_k<<<NB_N, 256, 0, stream>>>(rp, bsums, NB_N);
    scatter_k<<<NB_E_C + NB_N, 256, 0, stream>>>(ei, rp, count2, rank2, dis, edges,
                                                 hist, histcnt, perm);

    // layer 0: hb = relu(conv(x, W0, b0))
    gemm128_k<float><<<NB_G, 256, 0, stream>>>(x, WT, hw);
    agg_k<0><<<NB_A, 256, 0, stream>>>(hw, rp, edges, perm, selfn, b0,
                                       nullptr, nullptr, hb, nullptr, nullptr);
    // layer 1: hb = relu(bn0(conv(hb, W1, b1))) + hb
    gemm128_k<__bf16><<<NB_G, 256, 0, stream>>>(hb, WT + HD * HD, hw);
    agg_k<1><<<NB_A, 256, 0, stream>>>(hw, rp, edges, perm, selfn, b1,
                                       bnA0, bnB0, hb, nullptr, nullptr);
    // layer 2 (+ fused W3 projection): hw3 = (relu(bn1(conv(hb, W2, b2))) + hb) @ W3
    gemm128_k<__bf16><<<NB_G, 256, 0, stream>>>(hb, WT + 2 * HD * HD, hw);
    agg_k<2><<<NB_A, 256, 0, stream>>>(hw, rp, edges, perm, selfn, b2,
                                       bnA1, bnB1, hb, W3, hw3);
    // final aggregation + log_softmax
    final_k<<<NB_N, 256, 0, stream>>>(hw3, rp, edges, selfn, b3, out);
}

// Round 4
// 322.374 us; speedup vs baseline: 1.0959x; 1.0959x over previous
//
#include <hip/hip_runtime.h>
#include <hip/hip_bf16.h>
#include <type_traits>

#define NN 100000
#define NE 800000
#define HD 128
#define BN_EPS 1e-5f
#define NB_E_C 3125   // (NE+255)/256

typedef __bf16 bf16x8 __attribute__((ext_vector_type(8)));
typedef __bf16 bf16x2 __attribute__((ext_vector_type(2)));
typedef float  f32x4  __attribute__((ext_vector_type(4)));
typedef float  f32x2  __attribute__((ext_vector_type(2)));

// ---------------- CSR build ----------------

// fused: histogram+rank (blocks 0..NB_E_C-1), weight transpose (3 blocks),
// BN affine precompute (1 block)
__global__ __launch_bounds__(256) void count_prep_k(const int* __restrict__ ei, int* __restrict__ count,
                                                    int* __restrict__ rank,
                                                    const float* __restrict__ W0, const float* __restrict__ W1,
                                                    const float* __restrict__ W2, __bf16* __restrict__ WT,
                                                    const float* __restrict__ g0, const float* __restrict__ b0,
                                                    const float* __restrict__ m0, const float* __restrict__ v0,
                                                    const float* __restrict__ g1, const float* __restrict__ b1,
                                                    const float* __restrict__ m1, const float* __restrict__ v1,
                                                    float* __restrict__ A0, float* __restrict__ B0,
                                                    float* __restrict__ A1, float* __restrict__ B1) {
    int bid = blockIdx.x;
    int tid = threadIdx.x;
    if (bid < NB_E_C) {
        int e = bid * 256 + tid;
        if (e < NE) rank[e] = atomicAdd(&count[ei[NE + e]], 1);
    } else if (bid < NB_E_C + 3) {
        int w = bid - NB_E_C;
        const float* Ws[3] = {W0, W1, W2};
        const float* W = Ws[w];
        __bf16* T = WT + w * (HD * HD);
        #pragma unroll 4
        for (int it = 0; it < 64; ++it) {
            int idx = it * 256 + tid;          // idx = n*128 + k (writes coalesced)
            int n = idx >> 7, k = idx & 127;
            T[idx] = (__bf16)W[k * HD + n];
        }
    } else {
        if (tid < 128) {
            float a = g0[tid] * rsqrtf(v0[tid] + BN_EPS);
            A0[tid] = a; B0[tid] = b0[tid] - m0[tid] * a;
        } else {
            int u = tid - 128;
            float a = g1[u] * rsqrtf(v1[u] + BN_EPS);
            A1[u] = a; B1[u] = b1[u] - m1[u] * a;
        }
    }
}

// block-level exclusive scan of count + per-node norm terms
__global__ __launch_bounds__(256) void scan1_k(const int* __restrict__ count,
                                               int* __restrict__ rp, int* __restrict__ bsums,
                                               float* __restrict__ dis, float* __restrict__ selfn) {
    __shared__ int sm[256];
    int tid = threadIdx.x;
    int i = blockIdx.x * 256 + tid;
    int v = (i < NN) ? count[i] : 0;
    if (i < NN) {
        float deg = (float)v + 1.0f;
        float di = rsqrtf(deg);
        dis[i] = di;
        selfn[i] = di * di;
    }
    sm[tid] = v; __syncthreads();
    for (int off = 1; off < 256; off <<= 1) {
        int t = (tid >= off) ? sm[tid - off] : 0;
        __syncthreads();
        sm[tid] += t;
        __syncthreads();
    }
    if (i < NN) rp[i] = sm[tid] - v;           // exclusive within block
    if (tid == 255) bsums[blockIdx.x] = sm[tid];
}

// fused scan2+scan3: every block redundantly reduces bsums[0..blockIdx)
__global__ __launch_bounds__(256) void scan23_k(int* __restrict__ rp, const int* __restrict__ bsums, int nb) {
    __shared__ int sm[256];
    int tid = threadIdx.x;
    int b = blockIdx.x;
    int partial = 0;
    for (int i = tid; i < b; i += 256) partial += bsums[i];
    sm[tid] = partial; __syncthreads();
    #pragma unroll
    for (int off = 128; off > 0; off >>= 1) {
        if (tid < off) sm[tid] += sm[tid + off];
        __syncthreads();
    }
    int prefix = sm[0];
    int i = b * 256 + tid;
    if (i < NN) rp[i] += prefix;
    if (i == 0) rp[NN] = NE;
}

// scatter edges into CSR as packed (src, weight_bits); no atomics (rank precomputed)
__global__ __launch_bounds__(256) void scatter_k(const int* __restrict__ ei, const int* __restrict__ rp,
                                                 const int* __restrict__ rank, const float* __restrict__ dis,
                                                 uint2* __restrict__ edges) {
    int e = blockIdx.x * 256 + threadIdx.x;
    if (e >= NE) return;
    int s = ei[e], d = ei[NE + e];
    int pos = rp[d] + rank[e];
    edges[pos] = make_uint2((unsigned)s, __float_as_uint(dis[s] * dis[d]));
}

// ---------------- GEMM (layer 0 only): [N,128] fp32 @ WT[n][k] bf16 -> bf16 ----------------
// Column-permuted B mapping: MFMA tile ct, col m is fed channel n = m*8+ct,
// so each thread's 8 accumulator values per output row are channels
// m*8..m*8+7 -> one bf16x8 (16B/lane) coalesced store.
// LDS chunk-XOR swizzle with 4-bit key (n>>3): 4-way max on reads.

template <typename T>
__global__ __launch_bounds__(256, 5) void gemm128_k(const T* __restrict__ A, const __bf16* __restrict__ WTg,
                                                    __bf16* __restrict__ HW) {
    __shared__ __bf16 WL[128 * 128];   // 32 KiB -> 5 blocks/CU
    const int tid = threadIdx.x;
    const int wid  = __builtin_amdgcn_readfirstlane(tid >> 6);
    const int lane = tid & 63;
    const int m = lane & 15, quad = lane >> 4;
    const int row_base = blockIdx.x * 64 + wid * 16;

    // prefetch this lane's 4 A-fragments (k = ks*32 + quad*8) before the barrier
    int r = row_base + m;
    if (r >= NN) r = NN - 1;
    bf16x8 afr[4];
    if constexpr (std::is_same<T, float>::value) {
        const float4* ap = (const float4*)(A + (size_t)r * HD);
        #pragma unroll
        for (int ks = 0; ks < 4; ++ks) {
            float4 x0 = ap[ks * 8 + quad * 2], x1 = ap[ks * 8 + quad * 2 + 1];
            bf16x8 a;
            a[0] = (__bf16)x0.x; a[1] = (__bf16)x0.y; a[2] = (__bf16)x0.z; a[3] = (__bf16)x0.w;
            a[4] = (__bf16)x1.x; a[5] = (__bf16)x1.y; a[6] = (__bf16)x1.z; a[7] = (__bf16)x1.w;
            afr[ks] = a;
        }
    } else {
        const bf16x8* ap = (const bf16x8*)(A + (size_t)r * HD);
        #pragma unroll
        for (int ks = 0; ks < 4; ++ks) afr[ks] = ap[ks * 4 + quad];
    }

    // stage WT -> LDS with chunk-XOR swizzle: chunk c of row n lands at c^(n>>3)
    #pragma unroll
    for (int it = 0; it < 8; ++it) {
        int id = it * 256 + tid;          // chunk id
        int n = id >> 4, c = id & 15;     // row, 16B-chunk within row
        int cs = c ^ (n >> 3);
        *(uint4*)&WL[n * 128 + cs * 8] = *(const uint4*)(WTg + n * HD + c * 8);
    }
    __syncthreads();

    f32x4 acc[8];
    #pragma unroll
    for (int ct = 0; ct < 8; ++ct) acc[ct] = (f32x4){0.f, 0.f, 0.f, 0.f};

    #pragma unroll
    for (int ks = 0; ks < 4; ++ks) {
        #pragma unroll
        for (int ct = 0; ct < 8; ++ct) {
            int n = m * 8 + ct;                       // channel fed to tile ct, col m
            int cs = (ks * 4 + quad) ^ m;             // swizzled 16B chunk (key = n>>3 = m)
            bf16x8 bfr = *(const bf16x8*)&WL[n * 128 + cs * 8];
            acc[ct] = __builtin_amdgcn_mfma_f32_16x16x32_bf16(afr[ks], bfr, acc[ct], 0, 0, 0);
        }
    }

    // coalesced epilogue: one bf16x8 (16B) store per lane per row
    #pragma unroll
    for (int rr = 0; rr < 4; ++rr) {
        int row = row_base + quad * 4 + rr;
        if (row < NN) {
            bf16x8 v;
            #pragma unroll
            for (int ct = 0; ct < 8; ++ct) v[ct] = (__bf16)acc[ct][rr];
            *(bf16x8*)(HW + (size_t)row * HD + m * 8) = v;
        }
    }
}

// ---------------- helpers ----------------

__device__ __forceinline__ void acc8p(f32x2* acc, uint4 rv, float wt) {
    f32x2 w2 = {wt, wt};
    f32x2 x0 = {__uint_as_float(rv.x << 16), __uint_as_float(rv.x & 0xffff0000u)};
    f32x2 x1 = {__uint_as_float(rv.y << 16), __uint_as_float(rv.y & 0xffff0000u)};
    f32x2 x2 = {__uint_as_float(rv.z << 16), __uint_as_float(rv.z & 0xffff0000u)};
    f32x2 x3 = {__uint_as_float(rv.w << 16), __uint_as_float(rv.w & 0xffff0000u)};
    acc[0] = __builtin_elementwise_fma(x0, w2, acc[0]);
    acc[1] = __builtin_elementwise_fma(x1, w2, acc[1]);
    acc[2] = __builtin_elementwise_fma(x2, w2, acc[2]);
    acc[3] = __builtin_elementwise_fma(x3, w2, acc[3]);
}

// ---------------- layer-0 aggregation: hb = relu(agg(hw) + b0) ----------------
// 4 nodes per wave, 16 lanes per node, 4-deep pipelined gather (round-0 form).

__global__ __launch_bounds__(256) void agg0_k(const __bf16* __restrict__ hw, const int* __restrict__ rp,
                                              const uint2* __restrict__ edges,
                                              const float* __restrict__ selfn, const float* __restrict__ bias,
                                              __bf16* __restrict__ hb) {
    const int lane = threadIdx.x & 63;
    const int wid  = threadIdx.x >> 6;
    const int grp  = lane >> 4;
    const int m    = lane & 15;
    const int n = blockIdx.x * 16 + wid * 4 + grp;   // NN = 6250*16 exactly
    const int c0 = m * 8;
    const int L = NE - 1;

    const int e0 = rp[n], e1 = rp[n + 1];
    const float sn = selfn[n];
    uint4 rv_self = *(const uint4*)(hw + ((size_t)n << 7) + c0);

    f32x2 acc2[4];
    #pragma unroll
    for (int j = 0; j < 4; ++j) acc2[j] = (f32x2){0.f, 0.f};

    int e = e0;
    int cnt = e1 - e0;
    uint2 edA = edges[min(e,     L)];
    uint2 edB = edges[min(e + 1, L)];
    uint2 edC = edges[min(e + 2, L)];
    uint2 edD = edges[min(e + 3, L)];
    while (cnt >= 4) {
        uint4 r0 = *(const uint4*)(hw + ((size_t)edA.x << 7) + c0);
        uint4 r1 = *(const uint4*)(hw + ((size_t)edB.x << 7) + c0);
        uint4 r2 = *(const uint4*)(hw + ((size_t)edC.x << 7) + c0);
        uint4 r3 = *(const uint4*)(hw + ((size_t)edD.x << 7) + c0);
        uint2 nA = edges[min(e + 4, L)];
        uint2 nB = edges[min(e + 5, L)];
        uint2 nC = edges[min(e + 6, L)];
        uint2 nD = edges[min(e + 7, L)];
        acc8p(acc2, r0, __uint_as_float(edA.y));
        acc8p(acc2, r1, __uint_as_float(edB.y));
        acc8p(acc2, r2, __uint_as_float(edC.y));
        acc8p(acc2, r3, __uint_as_float(edD.y));
        edA = nA; edB = nB; edC = nC; edD = nD;
        e += 4; cnt -= 4;
    }
    if (cnt >= 2) {
        uint4 r0 = *(const uint4*)(hw + ((size_t)edA.x << 7) + c0);
        uint4 r1 = *(const uint4*)(hw + ((size_t)edB.x << 7) + c0);
        acc8p(acc2, r0, __uint_as_float(edA.y));
        acc8p(acc2, r1, __uint_as_float(edB.y));
        edA = edC;
        cnt -= 2;
    }
    if (cnt == 1) {
        uint4 rv = *(const uint4*)(hw + ((size_t)edA.x << 7) + c0);
        acc8p(acc2, rv, __uint_as_float(edA.y));
    }
    acc8p(acc2, rv_self, sn);

    float a8[8] = {acc2[0][0], acc2[0][1], acc2[1][0], acc2[1][1],
                   acc2[2][0], acc2[2][1], acc2[3][0], acc2[3][1]};
    float4 bs0 = *(const float4*)(bias + c0);
    float4 bs1 = *(const float4*)(bias + c0 + 4);
    float bf[8] = {bs0.x, bs0.y, bs0.z, bs0.w, bs1.x, bs1.y, bs1.z, bs1.w};
    bf16x8 v;
    #pragma unroll
    for (int j = 0; j < 8; ++j) v[j] = (__bf16)fmaxf(a8[j] + bf[j], 0.f);
    *(bf16x8*)(hb + ((size_t)n << 7) + c0) = v;
}

// ---------------- fused aggregation + weight multiply (layers 1,2) ----------------
// Linearity: conv(h,W) = (agg_h) W + b. Gather in h-space (same bytes as
// before), then per block of 16 nodes apply W via one 16x128 MFMA tile.
// Self row == residual row (one load). MODE 1: hbO = relu(bn(z)) + h;
// MODE 2: h2 = relu(bn(z)) + h, then hw3 = h2 . W3 (in-register + LDS reduce).

template <int MODE>
__global__ __launch_bounds__(256, 4) void aggw_k(const __bf16* __restrict__ hbI, const __bf16* __restrict__ WTg,
                                                 const int* __restrict__ rp, const uint2* __restrict__ edges,
                                                 const float* __restrict__ selfn, const float* __restrict__ bias,
                                                 const float* __restrict__ bnA, const float* __restrict__ bnB,
                                                 __bf16* __restrict__ hbO, const float* __restrict__ W3,
                                                 float2* __restrict__ hw3) {
    __shared__ __bf16 WLs[128 * 128];   // 32 KiB, staged W^T tile
    __shared__ __bf16 SL[16 * 128];     // 4 KiB, aggregated s rows (bf16)
    __shared__ __bf16 SelfL[16 * 128];  // 4 KiB, self/residual rows
    const int tid = threadIdx.x;
    const int wid  = __builtin_amdgcn_readfirstlane(tid >> 6);
    const int lane = tid & 63;
    const int quad = lane >> 4;         // gather: node-in-wave; mfma: D-row group
    const int m    = lane & 15;
    const int nn = wid * 4 + quad;      // node within block (0..15)
    const int n = blockIdx.x * 16 + nn;
    const int c0 = m * 8;
    const int L = NE - 1;

    // stage W^T -> LDS (consumed after the barrier; hides under the gather)
    #pragma unroll
    for (int it = 0; it < 8; ++it) {
        int id = it * 256 + tid;
        int r = id >> 4, c = id & 15;
        int cs = c ^ (r >> 3);
        *(uint4*)&WLs[r * 128 + cs * 8] = *(const uint4*)(WTg + r * HD + c * 8);
    }

    const int e0 = rp[n], e1 = rp[n + 1];
    const float sn = selfn[n];
    uint4 rv_self = *(const uint4*)(hbI + ((size_t)n << 7) + c0);

    f32x2 acc2[4];
    #pragma unroll
    for (int j = 0; j < 4; ++j) acc2[j] = (f32x2){0.f, 0.f};

    int e = e0;
    int cnt = e1 - e0;
    uint2 edA = edges[min(e,     L)];
    uint2 edB = edges[min(e + 1, L)];
    uint2 edC = edges[min(e + 2, L)];
    uint2 edD = edges[min(e + 3, L)];
    while (cnt >= 4) {
        uint4 r0 = *(const uint4*)(hbI + ((size_t)edA.x << 7) + c0);
        uint4 r1 = *(const uint4*)(hbI + ((size_t)edB.x << 7) + c0);
        uint4 r2 = *(const uint4*)(hbI + ((size_t)edC.x << 7) + c0);
        uint4 r3 = *(const uint4*)(hbI + ((size_t)edD.x << 7) + c0);
        uint2 nA = edges[min(e + 4, L)];
        uint2 nB = edges[min(e + 5, L)];
        uint2 nC = edges[min(e + 6, L)];
        uint2 nD = edges[min(e + 7, L)];
        acc8p(acc2, r0, __uint_as_float(edA.y));
        acc8p(acc2, r1, __uint_as_float(edB.y));
        acc8p(acc2, r2, __uint_as_float(edC.y));
        acc8p(acc2, r3, __uint_as_float(edD.y));
        edA = nA; edB = nB; edC = nC; edD = nD;
        e += 4; cnt -= 4;
    }
    if (cnt >= 2) {
        uint4 r0 = *(const uint4*)(hbI + ((size_t)edA.x << 7) + c0);
        uint4 r1 = *(const uint4*)(hbI + ((size_t)edB.x << 7) + c0);
        acc8p(acc2, r0, __uint_as_float(edA.y));
        acc8p(acc2, r1, __uint_as_float(edB.y));
        edA = edC;
        cnt -= 2;
    }
    if (cnt == 1) {
        uint4 rv = *(const uint4*)(hbI + ((size_t)edA.x << 7) + c0);
        acc8p(acc2, rv, __uint_as_float(edA.y));
    }
    acc8p(acc2, rv_self, sn);   // self-loop (pre-W, h-space)

    // write s (bf16) + self row into LDS, chunk-swizzled by node (4-bit key)
    {
        float a8[8] = {acc2[0][0], acc2[0][1], acc2[1][0], acc2[1][1],
                       acc2[2][0], acc2[2][1], acc2[3][0], acc2[3][1]};
        bf16x8 sv;
        #pragma unroll
        for (int j = 0; j < 8; ++j) sv[j] = (__bf16)a8[j];
        int pc = m ^ nn;                 // physical chunk (nn&15 == nn)
        *(bf16x8*)&SL[nn * 128 + pc * 8] = sv;
        *(uint4*)&SelfL[nn * 128 + pc * 8] = rv_self;
    }
    __syncthreads();

    // MFMA: z[16 nodes][128 ch] = s @ W; wave wid computes tiles ct=wid*2,+1
    bf16x8 afr[4];
    #pragma unroll
    for (int ks = 0; ks < 4; ++ks) {
        int pcR = (ks * 4 + quad) ^ m;
        afr[ks] = *(const bf16x8*)&SL[m * 128 + pcR * 8];
    }
    f32x4 acc[2];
    acc[0] = (f32x4){0.f, 0.f, 0.f, 0.f};
    acc[1] = (f32x4){0.f, 0.f, 0.f, 0.f};
    #pragma unroll
    for (int ks = 0; ks < 4; ++ks) {
        int pcR = (ks * 4 + quad) ^ m;
        #pragma unroll
        for (int t = 0; t < 2; ++t) {
            int ct = wid * 2 + t;
            int nW = m * 8 + ct;             // out-channel row in WLs (nW>>3 == m)
            bf16x8 bfr = *(const bf16x8*)&WLs[nW * 128 + pcR * 8];
            acc[t] = __builtin_amdgcn_mfma_f32_16x16x32_bf16(afr[ks], bfr, acc[t], 0, 0, 0);
        }
    }

    // epilogue in MFMA layout: thread holds nodes quad*4..+3, channels ch0,ch0+1
    const int ch0 = m * 8 + wid * 2;
    float2 bias2 = *(const float2*)(bias + ch0);
    float2 A2 = *(const float2*)(bnA + ch0);
    float2 B2 = *(const float2*)(bnB + ch0);
    float4 w3r;
    if (MODE == 2) w3r = *(const float4*)(W3 + ch0 * 2);
    float p0a[4], p1a[4];
    #pragma unroll
    for (int rr = 0; rr < 4; ++rr) {
        int nd = quad * 4 + rr;
        char* sp = (char*)SelfL + nd * 256 + ((m ^ nd) * 16) + wid * 4;
        unsigned sv = *(const unsigned*)sp;
        float s0 = __uint_as_float(sv << 16);
        float s1 = __uint_as_float(sv & 0xffff0000u);
        float z0 = acc[0][rr] + bias2.x;
        float z1 = acc[1][rr] + bias2.y;
        float h0 = fmaxf(fmaf(z0, A2.x, B2.x), 0.f) + s0;
        float h1 = fmaxf(fmaf(z1, A2.y, B2.y), 0.f) + s1;
        if (MODE == 1) {
            bf16x2 pr = {(__bf16)h0, (__bf16)h1};
            *(bf16x2*)sp = pr;          // in-place (disjoint bytes per thread)
        } else {
            p0a[rr] = h0 * w3r.x + h1 * w3r.z;
            p1a[rr] = h0 * w3r.y + h1 * w3r.w;
        }
    }

    if (MODE == 1) {
        __syncthreads();
        // coalesced store of updated rows
        uint4 outv = *(const uint4*)&SelfL[nn * 128 + (m ^ nn) * 8];
        *(uint4*)(hbO + ((size_t)n << 7) + c0) = outv;
    } else {
        // reduce p over the 16-lane m-dimension, then across waves via LDS
        #pragma unroll
        for (int rr = 0; rr < 4; ++rr) {
            #pragma unroll
            for (int o = 1; o < 16; o <<= 1) {
                p0a[rr] += __shfl_xor(p0a[rr], o);
                p1a[rr] += __shfl_xor(p1a[rr], o);
            }
        }
        __syncthreads();                 // all SL (afr) reads done
        float2* PL = (float2*)SL;        // reuse SL space: [16 nodes][4 waves]
        if (m == 0) {
            #pragma unroll
            for (int rr = 0; rr < 4; ++rr)
                PL[(quad * 4 + rr) * 4 + wid] = make_float2(p0a[rr], p1a[rr]);
        }
        __syncthreads();
        if (tid < 16) {
            float2 a = PL[tid * 4 + 0], b = PL[tid * 4 + 1];
            float2 c = PL[tid * 4 + 2], d = PL[tid * 4 + 3];
            hw3[blockIdx.x * 16 + tid] = make_float2(a.x + b.x + c.x + d.x,
                                                     a.y + b.y + c.y + d.y);
        }
    }
}

// ---------------- final: aggregate hw3 + log_softmax ----------------

__global__ __launch_bounds__(256) void final_k(const float2* __restrict__ hw3, const int* __restrict__ rp,
                                               const uint2* __restrict__ edges,
                                               const float* __restrict__ selfn, const float* __restrict__ b3,
                                               float* __restrict__ out) {
    int n = blockIdx.x * 256 + threadIdx.x;
    if (n >= NN) return;
    const int L = NE - 1;
    float a0 = 0.f, a1 = 0.f;
    int e0 = rp[n], e1 = rp[n + 1];
    int cnt = e1 - e0;
    uint2 edA = edges[min(e0,     L)];
    uint2 edB = edges[min(e0 + 1, L)];
    int e = e0;
    while (cnt >= 2) {
        float2 v0 = hw3[edA.x];
        float2 v1 = hw3[edB.x];
        float w0 = __uint_as_float(edA.y), w1 = __uint_as_float(edB.y);
        edA = edges[min(e + 2, L)];
        edB = edges[min(e + 3, L)];
        a0 = fmaf(w0, v0.x, a0); a1 = fmaf(w0, v0.y, a1);
        a0 = fmaf(w1, v1.x, a0); a1 = fmaf(w1, v1.y, a1);
        e += 2; cnt -= 2;
    }
    if (cnt == 1) {
        float2 v = hw3[edA.x];
        float w = __uint_as_float(edA.y);
        a0 = fmaf(w, v.x, a0); a1 = fmaf(w, v.y, a1);
    }
    float sn = selfn[n];
    float2 hv = hw3[n];
    float z0 = a0 + sn * hv.x + b3[0];
    float z1 = a1 + sn * hv.y + b3[1];
    float mx = fmaxf(z0, z1);
    float l = mx + logf(expf(z0 - mx) + expf(z1 - mx));
    out[n * 2 + 0] = z0 - l;
    out[n * 2 + 1] = z1 - l;
}

// ---------------- launch ----------------

extern "C" void kernel_launch(void* const* d_in, const int* in_sizes, int n_in,
                              void* d_out, int out_size, void* d_ws, size_t ws_size,
                              hipStream_t stream) {
    (void)in_sizes; (void)n_in; (void)out_size; (void)ws_size;

    const float* x   = (const float*)d_in[0];
    const int*   ei  = (const int*)d_in[1];
    const float* W0  = (const float*)d_in[2];
    const float* b0  = (const float*)d_in[3];
    const float* W1  = (const float*)d_in[4];
    const float* b1  = (const float*)d_in[5];
    const float* W2  = (const float*)d_in[6];
    const float* b2  = (const float*)d_in[7];
    const float* W3  = (const float*)d_in[8];
    const float* b3  = (const float*)d_in[9];
    const float* bn0g = (const float*)d_in[10];
    const float* bn0b = (const float*)d_in[11];
    const float* bn0m = (const float*)d_in[12];
    const float* bn0v = (const float*)d_in[13];
    const float* bn1g = (const float*)d_in[14];
    const float* bn1b = (const float*)d_in[15];
    const float* bn1m = (const float*)d_in[16];
    const float* bn1v = (const float*)d_in[17];
    float* out = (float*)d_out;

    char* p = (char*)d_ws;
    auto alloc = [&](size_t bytes) -> void* {
        void* r = (void*)p;
        p += (bytes + 255) & ~(size_t)255;
        return r;
    };
    __bf16*  hb    = (__bf16*)alloc((size_t)NN * HD * 2);   // h after layer 0
    __bf16*  hb2   = (__bf16*)alloc((size_t)NN * HD * 2);   // h after layer 1
    __bf16*  hw    = (__bf16*)alloc((size_t)NN * HD * 2);   // x @ W0
    float2*  hw3   = (float2*)alloc((size_t)NN * 8);
    float*   dis   = (float*)alloc((size_t)NN * 4);
    float*   selfn = (float*)alloc((size_t)NN * 4);
    int*     count = (int*)alloc((size_t)NN * 4);
    int*     rp    = (int*)alloc((size_t)(NN + 1) * 4);
    uint2*   edges = (uint2*)alloc((size_t)NE * 8);
    int*     rank  = (int*)alloc((size_t)NE * 4);
    int*     bsums = (int*)alloc((size_t)512 * 4);
    float*   bnA0  = (float*)alloc(128 * 4);
    float*   bnB0  = (float*)alloc(128 * 4);
    float*   bnA1  = (float*)alloc(128 * 4);
    float*   bnB1  = (float*)alloc(128 * 4);
    __bf16*  WT    = (__bf16*)alloc((size_t)3 * HD * HD * 2);  // transposed bf16 weights

    const int NB_N = (NN + 255) / 256;   // 391
    const int NB_G = (NN + 63) / 64;     // 1563 (GEMM: 64 rows/block)
    const int NB_A = (NN + 15) / 16;     // 6250 (agg: 16 nodes per block)

    hipMemsetAsync(count, 0, (size_t)NN * 4, stream);

    count_prep_k<<<NB_E_C + 4, 256, 0, stream>>>(ei, count, rank,
                                                 W0, W1, W2, WT,
                                                 bn0g, bn0b, bn0m, bn0v, bn1g, bn1b, bn1m, bn1v,
                                                 bnA0, bnB0, bnA1, bnB1);
    scan1_k<<<NB_N, 256, 0, stream>>>(count, rp, bsums, dis, selfn);
    scan23_k<<<NB_N, 256, 0, stream>>>(rp, bsums, NB_N);
    scatter_k<<<NB_E_C, 256, 0, stream>>>(ei, rp, rank, dis, edges);

    // layer 0: hb = relu(conv(x, W0, b0))
    gemm128_k<float><<<NB_G, 256, 0, stream>>>(x, WT, hw);
    agg0_k<<<NB_A, 256, 0, stream>>>(hw, rp, edges, selfn, b0, hb);
    // layer 1 (fused agg+W): hb2 = relu(bn0(agg(hb) @ W1 + b1)) + hb
    aggw_k<1><<<NB_A, 256, 0, stream>>>(hb, WT + HD * HD, rp, edges, selfn, b1,
                                        bnA0, bnB0, hb2, nullptr, nullptr);
    // layer 2 (fused agg+W+W3): hw3 = (relu(bn1(agg(hb2) @ W2 + b2)) + hb2) @ W3
    aggw_k<2><<<NB_A, 256, 0, stream>>>(hb2, WT + 2 * HD * HD, rp, edges, selfn, b2,
                                        bnA1, bnB1, nullptr, W3, hw3);
    // final aggregation + log_softmax
    final_k<<<NB_N, 256, 0, stream>>>(hw3, rp, edges, selfn, b3, out);
}